// Round 1
// baseline (958.833 us; speedup 1.0000x reference)
//
#include <hip/hip_runtime.h>
#include <stdint.h>

#define QD 2048
#define KD 1024
#define HID 1024
#define NH 16
#define HD 64
#define CMBD 3072   // QD + KD

typedef float  f32x4   __attribute__((ext_vector_type(4)));
typedef short  short8  __attribute__((ext_vector_type(8)));
typedef short  short4v __attribute__((ext_vector_type(4)));
typedef float  float4v __attribute__((ext_vector_type(4)));

__device__ inline float bf2f(short s) {
  unsigned u = ((unsigned)(unsigned short)s) << 16;
  return __builtin_bit_cast(float, u);
}
__device__ inline short f2bf(float f) {
  unsigned u = __builtin_bit_cast(unsigned, f);
  u = u + 0x7fff + ((u >> 16) & 1);
  return (short)(u >> 16);
}

// ---------------------------------------------------------------- conversions
__global__ void cvt_bf16(const float* __restrict__ s, short* __restrict__ d) {
  size_t i = ((size_t)blockIdx.x * blockDim.x + threadIdx.x) * 4;
  float4v v = *(const float4v*)(s + i);
  short4v o;
  o[0] = f2bf(v[0]); o[1] = f2bf(v[1]); o[2] = f2bf(v[2]); o[3] = f2bf(v[3]);
  *(short4v*)(d + i) = o;
}

// copy fp32 [rows][ncols] into bf16 [rows][ldd] at column offset embedded in d
__global__ void cvt_concat(const float* __restrict__ s, short* __restrict__ d,
                           int ncols4, int ldd) {
  int i = blockIdx.x * blockDim.x + threadIdx.x;
  int row = i / ncols4;
  int c4  = i - row * ncols4;
  float4v v = *(const float4v*)(s + (size_t)row * (ncols4 * 4) + c4 * 4);
  short4v o;
  o[0] = f2bf(v[0]); o[1] = f2bf(v[1]); o[2] = f2bf(v[2]); o[3] = f2bf(v[3]);
  *(short4v*)(d + (size_t)row * ldd + c4 * 4) = o;
}

// ---------------------------------------------------------------- GEMM (m97 structure)
// C[M,N] = A[M,K] * W[N,K]^T + bias, all bf16 in, bf16 out, fp32 accum.
// 128x128 tile, BK=32, 4 waves, 16x16x32 MFMA, global_load_lds width 16.
#define EPI_NONE 0
#define EPI_GELU 1

typedef const __attribute__((address_space(1))) void gvoid_t;
typedef __attribute__((address_space(3))) void lvoid_t;

template<int EPI>
__global__ __launch_bounds__(256)
void gemm_bt(const short* __restrict__ A, size_t lda,
             const short* __restrict__ W,      // [N][K], row-major
             const float* __restrict__ bias,   // [N]
             short* __restrict__ C, int N, int K) {
  __shared__ short lsA[128 * 32];
  __shared__ short lsB[128 * 32];
  const int tid  = threadIdx.x;
  const int lane = tid & 63;
  const int wave = tid >> 6;
  const size_t rowBase = (size_t)blockIdx.y * 128;
  const size_t colBase = (size_t)blockIdx.x * 128;

  f32x4 acc[4][4];
#pragma unroll
  for (int m = 0; m < 4; m++)
#pragma unroll
    for (int n = 0; n < 4; n++) acc[m][n] = (f32x4){0.f, 0.f, 0.f, 0.f};

  const int wrow = (wave >> 1) * 64;   // wave's sub-tile origin in tile
  const int wcol = (wave & 1) * 64;
  const int fr = lane & 15;            // fragment row/col index
  const int kq = lane >> 4;            // k-quad 0..3

  // staging geometry: segment s covers tile rows [s*16, s*16+16), 1024B each.
  const int trow_off = lane >> 2;         // 0..15
  const int tcol     = (lane & 3) * 8;    // element offset in k

  for (int kt = 0; kt < K; kt += 32) {
#pragma unroll
    for (int s2 = 0; s2 < 2; s2++) {
      const int s = wave * 2 + s2;
      const int trow = s * 16 + trow_off;
      const short* ga = A + (rowBase + trow) * lda + (size_t)(kt + tcol);
      __builtin_amdgcn_global_load_lds((gvoid_t*)ga,
          (lvoid_t*)&lsA[s * 512 + lane * 8], 16, 0, 0);
      const short* gb = W + (colBase + trow) * (size_t)K + (size_t)(kt + tcol);
      __builtin_amdgcn_global_load_lds((gvoid_t*)gb,
          (lvoid_t*)&lsB[s * 512 + lane * 8], 16, 0, 0);
    }
    asm volatile("s_waitcnt vmcnt(0)" ::: "memory");
    __syncthreads();

    short8 af[4], bf[4];
#pragma unroll
    for (int m = 0; m < 4; m++)
      af[m] = *(const short8*)&lsA[(wrow + m * 16 + fr) * 32 + kq * 8];
#pragma unroll
    for (int n = 0; n < 4; n++)
      bf[n] = *(const short8*)&lsB[(wcol + n * 16 + fr) * 32 + kq * 8];
#pragma unroll
    for (int m = 0; m < 4; m++)
#pragma unroll
      for (int n = 0; n < 4; n++)
        acc[m][n] = __builtin_amdgcn_mfma_f32_16x16x32_bf16(af[m], bf[n], acc[m][n], 0, 0, 0);
    __syncthreads();
  }

  // epilogue: C/D layout col = lane&15, row = (lane>>4)*4 + reg
#pragma unroll
  for (int m = 0; m < 4; m++) {
    const size_t row0 = rowBase + wrow + m * 16 + kq * 4;
#pragma unroll
    for (int n = 0; n < 4; n++) {
      const int col = (int)colBase + wcol + n * 16 + fr;
      const float bv = bias[col];
#pragma unroll
      for (int j = 0; j < 4; j++) {
        float x = acc[m][n][j] + bv;
        if (EPI == EPI_GELU) x = 0.5f * x * (1.f + erff(x * 0.70710678118f));
        C[(row0 + j) * (size_t)N + col] = f2bf(x);
      }
    }
  }
}

// ---------------------------------------------------------------- block reduce
__device__ inline float2 block_sum2(float a, float b, float* sc) {
#pragma unroll
  for (int o = 32; o >= 1; o >>= 1) {
    a += __shfl_down(a, o);
    b += __shfl_down(b, o);
  }
  const int lane = threadIdx.x & 63, w = threadIdx.x >> 6;
  const int nw = blockDim.x >> 6;
  if (lane == 0) { sc[w * 2] = a; sc[w * 2 + 1] = b; }
  __syncthreads();
  float ra = 0.f, rb = 0.f;
  for (int i = 0; i < nw; i++) { ra += sc[i * 2]; rb += sc[i * 2 + 1]; }
  __syncthreads();
  return make_float2(ra, rb);
}

// ---------------------------------------------------------------- fused LN(q),LN(k) + 16x16 attention
__global__ __launch_bounds__(256)
void attn_ln(const short* __restrict__ qp, const short* __restrict__ kp,
             const short* __restrict__ vk,
             const float* __restrict__ lnqw, const float* __restrict__ lnqb,
             const float* __restrict__ lnkw, const float* __restrict__ lnkb,
             short* __restrict__ att) {
  __shared__ float qs[HID];
  __shared__ float ks[NH * 65];   // padded stride 65 to kill bank conflicts
  __shared__ float vs[HID];
  __shared__ float aw[256];
  __shared__ float red[8];
  const int t = threadIdx.x;
  const size_t row = blockIdx.x;

  short4v q4 = *(const short4v*)(qp + row * HID + t * 4);
  short4v k4 = *(const short4v*)(kp + row * HID + t * 4);
  short4v v4 = *(const short4v*)(vk + row * HID + t * 4);
  float qv[4], kv[4];
  float sq = 0.f, sqq = 0.f, sk = 0.f, skk = 0.f;
#pragma unroll
  for (int i = 0; i < 4; i++) {
    qv[i] = bf2f(q4[i]); sq += qv[i]; sqq += qv[i] * qv[i];
    kv[i] = bf2f(k4[i]); sk += kv[i]; skk += kv[i] * kv[i];
  }
  float2 rq = block_sum2(sq, sqq, red);
  float mq = rq.x / HID, vq = rq.y / HID - mq * mq;
  float rsq = rsqrtf(vq + 1e-5f);
  float2 rk = block_sum2(sk, skk, red);
  float mk = rk.x / HID, vv = rk.y / HID - mk * mk;
  float rsk = rsqrtf(vv + 1e-5f);
#pragma unroll
  for (int i = 0; i < 4; i++) {
    const int idx = t * 4 + i;
    qs[idx] = (qv[i] - mq) * rsq * lnqw[idx] + lnqb[idx];
    ks[(idx >> 6) * 65 + (idx & 63)] = (kv[i] - mk) * rsk * lnkw[idx] + lnkb[idx];
    vs[idx] = bf2f(v4[i]);
  }
  __syncthreads();

  const int h = t >> 4, j = t & 15;
  float s = 0.f;
#pragma unroll 8
  for (int d = 0; d < 64; d++) s += qs[h * 64 + d] * ks[j * 65 + d];
  s *= 0.125f;  // 1/sqrt(64)
  float mx = s;
#pragma unroll
  for (int o = 8; o >= 1; o >>= 1) mx = fmaxf(mx, __shfl_xor(mx, o, 16));
  float e = __expf(s - mx);
  float sum = e;
#pragma unroll
  for (int o = 8; o >= 1; o >>= 1) sum += __shfl_xor(sum, o, 16);
  aw[t] = e / sum;
  __syncthreads();

  const int dB = (t & 15) * 4;
  float o0 = 0.f, o1 = 0.f, o2 = 0.f, o3 = 0.f;
#pragma unroll
  for (int jj = 0; jj < 16; jj++) {
    const float w = aw[h * 16 + jj];
    const float* vp = &vs[jj * 64 + dB];
    o0 += w * vp[0]; o1 += w * vp[1]; o2 += w * vp[2]; o3 += w * vp[3];
  }
  short4v o4;
  o4[0] = f2bf(o0); o4[1] = f2bf(o1); o4[2] = f2bf(o2); o4[3] = f2bf(o3);
  *(short4v*)(att + row * HID + h * 64 + dB) = o4;
}

// ---------------------------------------------------------------- gate: sigmoid(hg.Wg2+b)*sigmoid(hc.Wc2+b)
__global__ __launch_bounds__(256)
void gate_kernel(const short* __restrict__ hg, const short* __restrict__ hc,
                 const float* __restrict__ wg2, const float* __restrict__ bg2,
                 const float* __restrict__ wc2, const float* __restrict__ bc2,
                 float* __restrict__ eg) {
  __shared__ float red[8];
  const int t = threadIdx.x;
  const size_t row = blockIdx.x;
  short4v g4 = *(const short4v*)(hg + row * HID + t * 4);
  short4v c4 = *(const short4v*)(hc + row * HID + t * 4);
  float sg = 0.f, sc = 0.f;
#pragma unroll
  for (int i = 0; i < 4; i++) {
    sg += bf2f(g4[i]) * wg2[t * 4 + i];
    sc += bf2f(c4[i]) * wc2[t * 4 + i];
  }
  float2 r = block_sum2(sg, sc, red);
  if (t == 0) {
    float g = 1.f / (1.f + __expf(-(r.x + bg2[0])));
    float c = 1.f / (1.f + __expf(-(r.y + bc2[0])));
    eg[row] = g * c;
  }
}

// ---------------------------------------------------------------- final: out = qf + eg * LN_o(opre)
__global__ __launch_bounds__(256)
void final_kernel(const short* __restrict__ opre, const float* __restrict__ qf,
                  const float* __restrict__ eg,
                  const float* __restrict__ lnow, const float* __restrict__ lnob,
                  float* __restrict__ out) {
  __shared__ float red[8];
  const int t = threadIdx.x;
  const size_t row = blockIdx.x;
  short8 o8 = *(const short8*)(opre + row * QD + t * 8);
  float x[8];
  float s = 0.f, ss = 0.f;
#pragma unroll
  for (int i = 0; i < 8; i++) { x[i] = bf2f(o8[i]); s += x[i]; ss += x[i] * x[i]; }
  float2 r = block_sum2(s, ss, red);
  float m = r.x / QD, v = r.y / QD - m * m;
  float rs = rsqrtf(v + 1e-5f);
  float g = eg[row];
  float4v oa, ob;
#pragma unroll
  for (int i = 0; i < 8; i++) {
    const int c = t * 8 + i;
    float y = (x[i] - m) * rs * lnow[c] + lnob[c];
    float r2 = qf[row * QD + c] + g * y;
    if (i < 4) oa[i] = r2; else ob[i - 4] = r2;
  }
  *(float4v*)(out + row * QD + t * 8) = oa;
  *(float4v*)(out + row * QD + t * 8 + 4) = ob;
}

// ---------------------------------------------------------------- launch
extern "C" void kernel_launch(void* const* d_in, const int* in_sizes, int n_in,
                              void* d_out, int out_size, void* d_ws, size_t ws_size,
                              hipStream_t stream) {
  const float* qf   = (const float*)d_in[0];
  const float* kf   = (const float*)d_in[1];
  const float* Wq   = (const float*)d_in[2];
  const float* bq   = (const float*)d_in[3];
  const float* lnqw = (const float*)d_in[4];
  const float* lnqb = (const float*)d_in[5];
  const float* Wk   = (const float*)d_in[6];
  const float* bk   = (const float*)d_in[7];
  const float* lnkw = (const float*)d_in[8];
  const float* lnkb = (const float*)d_in[9];
  // d_in[10] Wvq, d_in[11] bvq: unused by the reference output
  const float* Wvk  = (const float*)d_in[12];
  const float* bvk  = (const float*)d_in[13];
  const float* Wo   = (const float*)d_in[14];
  const float* bo   = (const float*)d_in[15];
  const float* lnow = (const float*)d_in[16];
  const float* lnob = (const float*)d_in[17];
  const float* Wg1  = (const float*)d_in[18];
  const float* bg1  = (const float*)d_in[19];
  const float* Wg2  = (const float*)d_in[20];
  const float* bg2  = (const float*)d_in[21];
  const float* Wc1  = (const float*)d_in[22];
  const float* bc1  = (const float*)d_in[23];
  const float* Wc2  = (const float*)d_in[24];
  const float* bc2  = (const float*)d_in[25];

  const int rows = in_sizes[0] / QD;   // 16384

  char* ws = (char*)d_ws;
  size_t off = 0;
  auto alloc = [&](size_t bytes) -> char* {
    char* p = ws + off;
    off += (bytes + 255) & ~(size_t)255;
    return p;
  };
  short* cmb  = (short*)alloc((size_t)rows * CMBD * 2);   // bf16 [rows][3072] = qf||kf
  short* wqb  = (short*)alloc((size_t)HID * QD * 2);
  short* wkb  = (short*)alloc((size_t)HID * KD * 2);
  short* wvkb = (short*)alloc((size_t)HID * KD * 2);
  short* wob  = (short*)alloc((size_t)QD * HID * 2);
  short* wg1b = (short*)alloc((size_t)HID * CMBD * 2);
  short* wc1b = (short*)alloc((size_t)HID * CMBD * 2);
  short* hg   = (short*)alloc((size_t)rows * HID * 2);
  short* hc   = (short*)alloc((size_t)rows * HID * 2);
  short* qp   = (short*)alloc((size_t)rows * HID * 2);
  short* kp   = (short*)alloc((size_t)rows * HID * 2);
  short* vkb  = (short*)alloc((size_t)rows * HID * 2);
  float* eg   = (float*)alloc((size_t)rows * 4);
  short* att  = hg;    // reuse: hg consumed by gate_kernel before attn
  short* opre = cmb;   // reuse: cmb consumed by last GEMM before O-proj

  // --- convert inputs (concat) and weights to bf16
  cvt_concat<<<rows * 2, 256, 0, stream>>>(qf, cmb, QD / 4, CMBD);
  cvt_concat<<<rows, 256, 0, stream>>>(kf, cmb + QD, KD / 4, CMBD);
  cvt_bf16<<<(HID * QD / 4) / 256, 256, 0, stream>>>(Wq, wqb);
  cvt_bf16<<<(HID * KD / 4) / 256, 256, 0, stream>>>(Wk, wkb);
  cvt_bf16<<<(HID * KD / 4) / 256, 256, 0, stream>>>(Wvk, wvkb);
  cvt_bf16<<<(QD * HID / 4) / 256, 256, 0, stream>>>(Wo, wob);
  cvt_bf16<<<(HID * CMBD / 4) / 256, 256, 0, stream>>>(Wg1, wg1b);
  cvt_bf16<<<(HID * CMBD / 4) / 256, 256, 0, stream>>>(Wc1, wc1b);

  const dim3 blk(256);
  const int mt = rows / 128;
  // gate path first so hg/hc can be reused
  gemm_bt<EPI_GELU><<<dim3(HID / 128, mt), blk, 0, stream>>>(cmb, CMBD, wg1b, bg1, hg, HID, CMBD);
  gemm_bt<EPI_GELU><<<dim3(HID / 128, mt), blk, 0, stream>>>(cmb, CMBD, wc1b, bc1, hc, HID, CMBD);
  gate_kernel<<<rows, blk, 0, stream>>>(hg, hc, Wg2, bg2, Wc2, bc2, eg);
  // projections
  gemm_bt<EPI_NONE><<<dim3(HID / 128, mt), blk, 0, stream>>>(cmb, CMBD, wqb, bq, qp, HID, QD);
  gemm_bt<EPI_NONE><<<dim3(HID / 128, mt), blk, 0, stream>>>(cmb + QD, CMBD, wkb, bk, kp, HID, KD);
  gemm_bt<EPI_NONE><<<dim3(HID / 128, mt), blk, 0, stream>>>(cmb + QD, CMBD, wvkb, bvk, vkb, HID, KD);
  // attention (LN fused)
  attn_ln<<<rows, blk, 0, stream>>>(qp, kp, vkb, lnqw, lnqb, lnkw, lnkb, att);
  // output projection + final
  gemm_bt<EPI_NONE><<<dim3(QD / 128, mt), blk, 0, stream>>>(att, HID, wob, bo, opre, QD, HID);
  final_kernel<<<rows, blk, 0, stream>>>(opre, qf, eg, lnow, lnob, (float*)d_out);
}

// Round 2
// 847.685 us; speedup vs baseline: 1.1311x; 1.1311x over previous
//
#include <hip/hip_runtime.h>
#include <stdint.h>

#define QD 2048
#define KD 1024
#define HID 1024
#define NH 16
#define HD 64
#define CMBD 3072   // QD + KD

typedef float  f32x4   __attribute__((ext_vector_type(4)));
typedef short  short8  __attribute__((ext_vector_type(8)));
typedef short  short4v __attribute__((ext_vector_type(4)));
typedef float  float4v __attribute__((ext_vector_type(4)));

__device__ inline float bf2f(short s) {
  unsigned u = ((unsigned)(unsigned short)s) << 16;
  return __builtin_bit_cast(float, u);
}
__device__ inline short f2bf(float f) {
  unsigned u = __builtin_bit_cast(unsigned, f);
  u = u + 0x7fff + ((u >> 16) & 1);
  return (short)(u >> 16);
}

// ---------------------------------------------------------------- conversions
__global__ void cvt_bf16(const float* __restrict__ s, short* __restrict__ d) {
  size_t i = ((size_t)blockIdx.x * blockDim.x + threadIdx.x) * 4;
  float4v v = *(const float4v*)(s + i);
  short4v o;
  o[0] = f2bf(v[0]); o[1] = f2bf(v[1]); o[2] = f2bf(v[2]); o[3] = f2bf(v[3]);
  *(short4v*)(d + i) = o;
}

// copy fp32 [rows][ncols] into bf16 [rows][ldd] at column offset embedded in d
__global__ void cvt_concat(const float* __restrict__ s, short* __restrict__ d,
                           int ncols4, int ldd) {
  int i = blockIdx.x * blockDim.x + threadIdx.x;
  int row = i / ncols4;
  int c4  = i - row * ncols4;
  float4v v = *(const float4v*)(s + (size_t)row * (ncols4 * 4) + c4 * 4);
  short4v o;
  o[0] = f2bf(v[0]); o[1] = f2bf(v[1]); o[2] = f2bf(v[2]); o[3] = f2bf(v[3]);
  *(short4v*)(d + (size_t)row * ldd + c4 * 4) = o;
}

// ---------------------------------------------------------------- GEMM (m97 structure + XCD swizzle)
// C[M,N] = A[M,K] * W[N,K]^T + bias, all bf16 in, bf16 out, fp32 accum.
// 128x128 tile, BK=32, 4 waves, 16x16x32 MFMA, global_load_lds width 16.
#define EPI_NONE 0
#define EPI_GELU 1

typedef const __attribute__((address_space(1))) void gvoid_t;
typedef __attribute__((address_space(3))) void lvoid_t;

template<int EPI>
__global__ __launch_bounds__(256)
void gemm_bt(const short* __restrict__ A, size_t lda,
             const short* __restrict__ W,      // [N][K], row-major
             const float* __restrict__ bias,   // [N]
             short* __restrict__ C, int N, int K) {
  __shared__ short lsA[128 * 32];
  __shared__ short lsB[128 * 32];
  const int tid  = threadIdx.x;
  const int lane = tid & 63;
  const int wave = tid >> 6;

  // bijective XCD swizzle: launch-order id -> contiguous chunk per XCD.
  // Requires nwg % 8 == 0 (all our grids satisfy this).
  const int nwg = gridDim.x * gridDim.y;
  const int lin = blockIdx.y * gridDim.x + blockIdx.x;
  const int cpx = nwg >> 3;
  const int nid = (lin & 7) * cpx + (lin >> 3);
  const int bx = nid % gridDim.x;   // gridDim.x is 8 or 16 (pow2): cheap
  const int by = nid / gridDim.x;

  const size_t rowBase = (size_t)by * 128;
  const size_t colBase = (size_t)bx * 128;

  f32x4 acc[4][4];
#pragma unroll
  for (int m = 0; m < 4; m++)
#pragma unroll
    for (int n = 0; n < 4; n++) acc[m][n] = (f32x4){0.f, 0.f, 0.f, 0.f};

  const int wrow = (wave >> 1) * 64;   // wave's sub-tile origin in tile
  const int wcol = (wave & 1) * 64;
  const int fr = lane & 15;            // fragment row/col index
  const int kq = lane >> 4;            // k-quad 0..3

  // staging geometry: segment s covers tile rows [s*16, s*16+16), 1024B each.
  const int trow_off = lane >> 2;         // 0..15
  const int tcol     = (lane & 3) * 8;    // element offset in k

  for (int kt = 0; kt < K; kt += 32) {
#pragma unroll
    for (int s2 = 0; s2 < 2; s2++) {
      const int s = wave * 2 + s2;
      const int trow = s * 16 + trow_off;
      const short* ga = A + (rowBase + trow) * lda + (size_t)(kt + tcol);
      __builtin_amdgcn_global_load_lds((gvoid_t*)ga,
          (lvoid_t*)&lsA[s * 512 + lane * 8], 16, 0, 0);
      const short* gb = W + (colBase + trow) * (size_t)K + (size_t)(kt + tcol);
      __builtin_amdgcn_global_load_lds((gvoid_t*)gb,
          (lvoid_t*)&lsB[s * 512 + lane * 8], 16, 0, 0);
    }
    asm volatile("s_waitcnt vmcnt(0)" ::: "memory");
    __syncthreads();

    short8 af[4], bf[4];
#pragma unroll
    for (int m = 0; m < 4; m++)
      af[m] = *(const short8*)&lsA[(wrow + m * 16 + fr) * 32 + kq * 8];
#pragma unroll
    for (int n = 0; n < 4; n++)
      bf[n] = *(const short8*)&lsB[(wcol + n * 16 + fr) * 32 + kq * 8];
#pragma unroll
    for (int m = 0; m < 4; m++)
#pragma unroll
      for (int n = 0; n < 4; n++)
        acc[m][n] = __builtin_amdgcn_mfma_f32_16x16x32_bf16(af[m], bf[n], acc[m][n], 0, 0, 0);
    __syncthreads();
  }

  // epilogue: C/D layout col = lane&15, row = (lane>>4)*4 + reg
#pragma unroll
  for (int m = 0; m < 4; m++) {
    const size_t row0 = rowBase + wrow + m * 16 + kq * 4;
#pragma unroll
    for (int n = 0; n < 4; n++) {
      const int col = (int)colBase + wcol + n * 16 + fr;
      const float bv = bias[col];
#pragma unroll
      for (int j = 0; j < 4; j++) {
        float x = acc[m][n][j] + bv;
        if (EPI == EPI_GELU) x = 0.5f * x * (1.f + erff(x * 0.70710678118f));
        C[(row0 + j) * (size_t)N + col] = f2bf(x);
      }
    }
  }
}

// ---------------------------------------------------------------- block reduce
__device__ inline float2 block_sum2(float a, float b, float* sc) {
#pragma unroll
  for (int o = 32; o >= 1; o >>= 1) {
    a += __shfl_down(a, o);
    b += __shfl_down(b, o);
  }
  const int lane = threadIdx.x & 63, w = threadIdx.x >> 6;
  const int nw = blockDim.x >> 6;
  if (lane == 0) { sc[w * 2] = a; sc[w * 2 + 1] = b; }
  __syncthreads();
  float ra = 0.f, rb = 0.f;
  for (int i = 0; i < nw; i++) { ra += sc[i * 2]; rb += sc[i * 2 + 1]; }
  __syncthreads();
  return make_float2(ra, rb);
}

// ---------------------------------------------------------------- fused LN(q),LN(k) + 16x16 attention
// kv is packed [rows][2048]: k = cols 0..1023, v = cols 1024..2047
__global__ __launch_bounds__(256)
void attn_ln(const short* __restrict__ qp, const short* __restrict__ kv,
             const float* __restrict__ lnqw, const float* __restrict__ lnqb,
             const float* __restrict__ lnkw, const float* __restrict__ lnkb,
             short* __restrict__ att) {
  __shared__ float qs[HID];
  __shared__ float ks[NH * 65];   // padded stride 65 to kill bank conflicts
  __shared__ float vs[HID];
  __shared__ float aw[256];
  __shared__ float red[8];
  const int t = threadIdx.x;
  const size_t row = blockIdx.x;

  short4v q4 = *(const short4v*)(qp + row * HID + t * 4);
  short4v k4 = *(const short4v*)(kv + row * 2048 + t * 4);
  short4v v4 = *(const short4v*)(kv + row * 2048 + 1024 + t * 4);
  float qv[4], kvv[4];
  float sq = 0.f, sqq = 0.f, sk = 0.f, skk = 0.f;
#pragma unroll
  for (int i = 0; i < 4; i++) {
    qv[i] = bf2f(q4[i]); sq += qv[i]; sqq += qv[i] * qv[i];
    kvv[i] = bf2f(k4[i]); sk += kvv[i]; skk += kvv[i] * kvv[i];
  }
  float2 rq = block_sum2(sq, sqq, red);
  float mq = rq.x / HID, vq = rq.y / HID - mq * mq;
  float rsq = rsqrtf(vq + 1e-5f);
  float2 rk = block_sum2(sk, skk, red);
  float mk = rk.x / HID, vv = rk.y / HID - mk * mk;
  float rsk = rsqrtf(vv + 1e-5f);
#pragma unroll
  for (int i = 0; i < 4; i++) {
    const int idx = t * 4 + i;
    qs[idx] = (qv[i] - mq) * rsq * lnqw[idx] + lnqb[idx];
    ks[(idx >> 6) * 65 + (idx & 63)] = (kvv[i] - mk) * rsk * lnkw[idx] + lnkb[idx];
    vs[idx] = bf2f(v4[i]);
  }
  __syncthreads();

  const int h = t >> 4, j = t & 15;
  float s = 0.f;
#pragma unroll 8
  for (int d = 0; d < 64; d++) s += qs[h * 64 + d] * ks[j * 65 + d];
  s *= 0.125f;  // 1/sqrt(64)
  float mx = s;
#pragma unroll
  for (int o = 8; o >= 1; o >>= 1) mx = fmaxf(mx, __shfl_xor(mx, o, 16));
  float e = __expf(s - mx);
  float sum = e;
#pragma unroll
  for (int o = 8; o >= 1; o >>= 1) sum += __shfl_xor(sum, o, 16);
  aw[t] = e / sum;
  __syncthreads();

  const int dB = (t & 15) * 4;
  float o0 = 0.f, o1 = 0.f, o2 = 0.f, o3 = 0.f;
#pragma unroll
  for (int jj = 0; jj < 16; jj++) {
    const float w = aw[h * 16 + jj];
    const float* vp = &vs[jj * 64 + dB];
    o0 += w * vp[0]; o1 += w * vp[1]; o2 += w * vp[2]; o3 += w * vp[3];
  }
  short4v o4;
  o4[0] = f2bf(o0); o4[1] = f2bf(o1); o4[2] = f2bf(o2); o4[3] = f2bf(o3);
  *(short4v*)(att + row * HID + h * 64 + dB) = o4;
}

// ---------------------------------------------------------------- gate: sigmoid(hg.Wg2+b)*sigmoid(hc.Wc2+b)
// hgc packed [rows][2048]: hg = cols 0..1023, hc = cols 1024..2047
__global__ __launch_bounds__(256)
void gate_kernel(const short* __restrict__ hgc,
                 const float* __restrict__ wg2, const float* __restrict__ bg2,
                 const float* __restrict__ wc2, const float* __restrict__ bc2,
                 float* __restrict__ eg) {
  __shared__ float red[8];
  const int t = threadIdx.x;
  const size_t row = blockIdx.x;
  short4v g4 = *(const short4v*)(hgc + row * 2048 + t * 4);
  short4v c4 = *(const short4v*)(hgc + row * 2048 + 1024 + t * 4);
  float sg = 0.f, sc = 0.f;
#pragma unroll
  for (int i = 0; i < 4; i++) {
    sg += bf2f(g4[i]) * wg2[t * 4 + i];
    sc += bf2f(c4[i]) * wc2[t * 4 + i];
  }
  float2 r = block_sum2(sg, sc, red);
  if (t == 0) {
    float g = 1.f / (1.f + __expf(-(r.x + bg2[0])));
    float c = 1.f / (1.f + __expf(-(r.y + bc2[0])));
    eg[row] = g * c;
  }
}

// ---------------------------------------------------------------- final: out = qf + eg * LN_o(opre)
__global__ __launch_bounds__(256)
void final_kernel(const short* __restrict__ opre, const float* __restrict__ qf,
                  const float* __restrict__ eg,
                  const float* __restrict__ lnow, const float* __restrict__ lnob,
                  float* __restrict__ out) {
  __shared__ float red[8];
  const int t = threadIdx.x;
  const size_t row = blockIdx.x;
  short8 o8 = *(const short8*)(opre + row * QD + t * 8);
  float x[8];
  float s = 0.f, ss = 0.f;
#pragma unroll
  for (int i = 0; i < 8; i++) { x[i] = bf2f(o8[i]); s += x[i]; ss += x[i] * x[i]; }
  float2 r = block_sum2(s, ss, red);
  float m = r.x / QD, v = r.y / QD - m * m;
  float rs = rsqrtf(v + 1e-5f);
  float g = eg[row];
  float4v oa, ob;
#pragma unroll
  for (int i = 0; i < 8; i++) {
    const int c = t * 8 + i;
    float y = (x[i] - m) * rs * lnow[c] + lnob[c];
    float r2 = qf[row * QD + c] + g * y;
    if (i < 4) oa[i] = r2; else ob[i - 4] = r2;
  }
  *(float4v*)(out + row * QD + t * 8) = oa;
  *(float4v*)(out + row * QD + t * 8 + 4) = ob;
}

// ---------------------------------------------------------------- launch
extern "C" void kernel_launch(void* const* d_in, const int* in_sizes, int n_in,
                              void* d_out, int out_size, void* d_ws, size_t ws_size,
                              hipStream_t stream) {
  const float* qf   = (const float*)d_in[0];
  const float* kf   = (const float*)d_in[1];
  const float* Wq   = (const float*)d_in[2];
  const float* bq   = (const float*)d_in[3];
  const float* lnqw = (const float*)d_in[4];
  const float* lnqb = (const float*)d_in[5];
  const float* Wk   = (const float*)d_in[6];
  const float* bk   = (const float*)d_in[7];
  const float* lnkw = (const float*)d_in[8];
  const float* lnkb = (const float*)d_in[9];
  // d_in[10] Wvq, d_in[11] bvq: unused by the reference output
  const float* Wvk  = (const float*)d_in[12];
  const float* bvk  = (const float*)d_in[13];
  const float* Wo   = (const float*)d_in[14];
  const float* bo   = (const float*)d_in[15];
  const float* lnow = (const float*)d_in[16];
  const float* lnob = (const float*)d_in[17];
  const float* Wg1  = (const float*)d_in[18];
  const float* bg1  = (const float*)d_in[19];
  const float* Wg2  = (const float*)d_in[20];
  const float* bg2  = (const float*)d_in[21];
  const float* Wc1  = (const float*)d_in[22];
  const float* bc1  = (const float*)d_in[23];
  const float* Wc2  = (const float*)d_in[24];
  const float* bc2  = (const float*)d_in[25];

  const int rows = in_sizes[0] / QD;   // 16384

  char* ws = (char*)d_ws;
  size_t off = 0;
  auto alloc = [&](size_t bytes) -> char* {
    char* p = ws + off;
    off += (bytes + 255) & ~(size_t)255;
    return p;
  };
  short* cmb  = (short*)alloc((size_t)rows * CMBD * 2);   // bf16 [rows][3072] = qf||kf
  short* wqb  = (short*)alloc((size_t)HID * QD * 2);
  short* wkv  = (short*)alloc((size_t)2 * HID * KD * 2);  // Wk ‖ Wvk, [2048][1024]
  short* wob  = (short*)alloc((size_t)QD * HID * 2);
  short* wgc  = (short*)alloc((size_t)2 * HID * CMBD * 2);// Wg1 ‖ Wc1, [2048][3072]
  short* hgc  = (short*)alloc((size_t)rows * 2048 * 2);   // gelu(g1) ‖ gelu(c1)
  short* qp   = (short*)alloc((size_t)rows * HID * 2);
  short* kvp  = (short*)alloc((size_t)rows * 2048 * 2);   // k ‖ v_k
  float* eg   = (float*)alloc((size_t)rows * 4);
  float* bgc  = (float*)alloc(2048 * 4);                  // bg1 ‖ bc1
  float* bkv  = (float*)alloc(2048 * 4);                  // bk ‖ bvk
  short* att  = hgc;   // reuse: hgc consumed by gate_kernel before attn
  short* opre = cmb;   // reuse: cmb consumed by Q/KV GEMMs before O-proj

  // --- pack biases (d2d, graph-capturable)
  hipMemcpyAsync(bgc, bg1, HID * 4, hipMemcpyDeviceToDevice, stream);
  hipMemcpyAsync(bgc + HID, bc1, HID * 4, hipMemcpyDeviceToDevice, stream);
  hipMemcpyAsync(bkv, bk, HID * 4, hipMemcpyDeviceToDevice, stream);
  hipMemcpyAsync(bkv + HID, bvk, HID * 4, hipMemcpyDeviceToDevice, stream);

  // --- convert inputs (concat) and weights to bf16
  cvt_concat<<<rows * 2, 256, 0, stream>>>(qf, cmb, QD / 4, CMBD);
  cvt_concat<<<rows, 256, 0, stream>>>(kf, cmb + QD, KD / 4, CMBD);
  cvt_bf16<<<(HID * QD / 4) / 256, 256, 0, stream>>>(Wq, wqb);
  cvt_bf16<<<(HID * KD / 4) / 256, 256, 0, stream>>>(Wk, wkv);
  cvt_bf16<<<(HID * KD / 4) / 256, 256, 0, stream>>>(Wvk, wkv + (size_t)HID * KD);
  cvt_bf16<<<(QD * HID / 4) / 256, 256, 0, stream>>>(Wo, wob);
  cvt_bf16<<<(HID * CMBD / 4) / 256, 256, 0, stream>>>(Wg1, wgc);
  cvt_bf16<<<(HID * CMBD / 4) / 256, 256, 0, stream>>>(Wc1, wgc + (size_t)HID * CMBD);

  const dim3 blk(256);
  const int mt = rows / 128;
  // fused gate GEMM: [rows,3072] x [2048,3072]^T -> hgc, GELU epilogue
  gemm_bt<EPI_GELU><<<dim3(2048 / 128, mt), blk, 0, stream>>>(cmb, CMBD, wgc, bgc, hgc, 2048, CMBD);
  gate_kernel<<<rows, blk, 0, stream>>>(hgc, Wg2, bg2, Wc2, bc2, eg);
  // projections: Q; fused K‖Vk
  gemm_bt<EPI_NONE><<<dim3(HID / 128, mt), blk, 0, stream>>>(cmb, CMBD, wqb, bq, qp, HID, QD);
  gemm_bt<EPI_NONE><<<dim3(2048 / 128, mt), blk, 0, stream>>>(cmb + QD, CMBD, wkv, bkv, kvp, 2048, KD);
  // attention (LN fused)
  attn_ln<<<rows, blk, 0, stream>>>(qp, kvp, lnqw, lnqb, lnkw, lnkb, att);
  // output projection + final
  gemm_bt<EPI_NONE><<<dim3(QD / 128, mt), blk, 0, stream>>>(att, HID, wob, bo, opre, QD, HID);
  final_kernel<<<rows, blk, 0, stream>>>(opre, qf, eg, lnow, lnob, (float*)d_out);
}

// Round 3
// 657.090 us; speedup vs baseline: 1.4592x; 1.2901x over previous
//
#include <hip/hip_runtime.h>
#include <stdint.h>

#define QD 2048
#define KD 1024
#define HID 1024
#define NH 16
#define HD 64
#define CMBD 3072   // QD + KD

typedef float  f32x4   __attribute__((ext_vector_type(4)));
typedef short  short8  __attribute__((ext_vector_type(8)));
typedef short  short4v __attribute__((ext_vector_type(4)));
typedef float  float4v __attribute__((ext_vector_type(4)));

__device__ inline float bf2f(short s) {
  unsigned u = ((unsigned)(unsigned short)s) << 16;
  return __builtin_bit_cast(float, u);
}
__device__ inline short f2bf(float f) {
  unsigned u = __builtin_bit_cast(unsigned, f);
  u = u + 0x7fff + ((u >> 16) & 1);
  return (short)(u >> 16);
}

// ---------------------------------------------------------------- conversions
__global__ void cvt_bf16(const float* __restrict__ s, short* __restrict__ d) {
  size_t i = ((size_t)blockIdx.x * blockDim.x + threadIdx.x) * 4;
  float4v v = *(const float4v*)(s + i);
  short4v o;
  o[0] = f2bf(v[0]); o[1] = f2bf(v[1]); o[2] = f2bf(v[2]); o[3] = f2bf(v[3]);
  *(short4v*)(d + i) = o;
}

__global__ void cvt_concat(const float* __restrict__ s, short* __restrict__ d,
                           int ncols4, int ldd) {
  int i = blockIdx.x * blockDim.x + threadIdx.x;
  int row = i / ncols4;
  int c4  = i - row * ncols4;
  float4v v = *(const float4v*)(s + (size_t)row * (ncols4 * 4) + c4 * 4);
  short4v o;
  o[0] = f2bf(v[0]); o[1] = f2bf(v[1]); o[2] = f2bf(v[2]); o[3] = f2bf(v[3]);
  *(short4v*)(d + (size_t)row * ldd + c4 * 4) = o;
}

// ---------------------------------------------------------------- 256x256 deep-pipeline GEMM
// C[M,N] = A[M,K] * W[N,K]^T + bias. bf16 in/out, fp32 accum.
// 8 waves (2M x 4N), per-wave 128x64 C. K-half granularity 32; ring of 4 LDS
// slots (32KB each: A 16KB | B 16KB). Counted vmcnt pipeline (3 halves ahead).
// LDS swizzle: 16B-slot ^= (row>>1)&3, involution; applied on gload_lds SOURCE
// and ds_read address (linear LDS dest per HW requirement).
#define EPI_NONE 0
#define EPI_GELU 1

typedef const __attribute__((address_space(1))) void gvoid_t;
typedef __attribute__((address_space(3))) void lvoid_t;

#define WAIT_VM(n) asm volatile("s_waitcnt vmcnt(" #n ")" ::: "memory")

__device__ __forceinline__ void stage_half(short* sl, const short* A, size_t lda,
                                           const short* W, size_t ldw,
                                           size_t rowA, size_t rowB, int kbase, int tid) {
  const int grow  = tid >> 2;                          // 0..127 (+128 on pass 1)
  const int slotx = (tid & 3) ^ ((tid >> 3) & 3);      // pre-swizzled source granule
  const int gcol  = kbase + slotx * 8;
#pragma unroll
  for (int p = 0; p < 2; p++) {
    const short* ga = A + (rowA + p * 128 + grow) * lda + gcol;
    __builtin_amdgcn_global_load_lds((gvoid_t*)ga,
        (lvoid_t*)(sl + p * 4096 + tid * 8), 16, 0, 0);
    const short* gb = W + (rowB + p * 128 + grow) * ldw + gcol;
    __builtin_amdgcn_global_load_lds((gvoid_t*)gb,
        (lvoid_t*)(sl + 8192 + p * 4096 + tid * 8), 16, 0, 0);
  }
}

template<int EPI>
__global__ __launch_bounds__(512, 2)
void gemm256(const short* __restrict__ A, size_t lda,
             const short* __restrict__ W,      // [N][K] row-major
             const float* __restrict__ bias,
             short* __restrict__ C, int N, int K) {
  extern __shared__ short ls[];                // 4 slots x 16384 shorts = 128 KiB
  const int tid  = threadIdx.x;
  const int lane = tid & 63;
  const int wave = tid >> 6;
  const int wm = wave >> 2, wn = wave & 3;
  const int fr = lane & 15, kq4 = lane >> 4;

  // bijective XCD swizzle (all grids have nwg % 8 == 0)
  const int nwg = gridDim.x * gridDim.y;
  const int lin = blockIdx.y * gridDim.x + blockIdx.x;
  const int cpx = nwg >> 3;
  const int nid = (lin & 7) * cpx + (lin >> 3);
  const int bx = nid % gridDim.x, by = nid / gridDim.x;
  const size_t rowBase = (size_t)by * 256;
  const size_t colBase = (size_t)bx * 256;

  const int NK2 = K >> 5;                      // number of 32-wide K halves

  f32x4 acc[8][4];
#pragma unroll
  for (int mi = 0; mi < 8; mi++)
#pragma unroll
    for (int ni = 0; ni < 4; ni++) acc[mi][ni] = (f32x4){0.f, 0.f, 0.f, 0.f};

  const int slot_x = (fr >> 1) & 3;
  const int axk = (kq4 ^ slot_x) * 8;          // swizzled 16B slot -> element offset
  const int abase = (wm * 128 + fr) * 32 + axk;   // + mi*512
  const int bbase = (wn * 64 + fr) * 32 + axk;    // + ni*512

  // prologue: stage halves 0,1,2
  stage_half(ls + 0 * 16384, A, lda, W, (size_t)K, rowBase, colBase, 0, tid);
  stage_half(ls + 1 * 16384, A, lda, W, (size_t)K, rowBase, colBase, 32, tid);
  stage_half(ls + 2 * 16384, A, lda, W, (size_t)K, rowBase, colBase, 64, tid);
  WAIT_VM(8);                                   // half 0 landed (own)
  __builtin_amdgcn_s_barrier();                 // all waves' half 0 landed

  for (int h = 0; h < NK2; ++h) {
    const short* sl = ls + (h & 3) * 16384;
    short8 af[8], bf[4];
#pragma unroll
    for (int mi = 0; mi < 8; mi++)
      af[mi] = *(const short8*)(sl + abase + mi * 512);
#pragma unroll
    for (int ni = 0; ni < 4; ni++)
      bf[ni] = *(const short8*)(sl + 8192 + bbase + ni * 512);

    if (h + 3 < NK2)                            // stage into slot consumed at phase h-1
      stage_half(ls + ((h + 3) & 3) * 16384, A, lda, W, (size_t)K,
                 rowBase, colBase, (h + 3) * 32, tid);

    __builtin_amdgcn_s_setprio(1);
#pragma unroll
    for (int mi = 0; mi < 8; mi++)
#pragma unroll
      for (int ni = 0; ni < 4; ni++)
        acc[mi][ni] = __builtin_amdgcn_mfma_f32_16x16x32_bf16(af[mi], bf[ni], acc[mi][ni], 0, 0, 0);
    __builtin_amdgcn_s_setprio(0);

    asm volatile("s_waitcnt lgkmcnt(0)" ::: "memory");  // slot reads drained before reuse
    const int rem = NK2 - 2 - h;                // halves staged after h+1
    if (rem >= 2)      { WAIT_VM(8); }          // h+1 landed, h+2/h+3 in flight
    else if (rem == 1) { WAIT_VM(4); }
    else               { WAIT_VM(0); }
    __builtin_amdgcn_s_barrier();
  }

  // epilogue: C/D layout col = lane&15, row = (lane>>4)*4 + reg
#pragma unroll
  for (int mi = 0; mi < 8; mi++) {
    const size_t row0 = rowBase + wm * 128 + mi * 16 + kq4 * 4;
#pragma unroll
    for (int ni = 0; ni < 4; ni++) {
      const int col = (int)colBase + wn * 64 + ni * 16 + fr;
      const float bv = bias[col];
#pragma unroll
      for (int j = 0; j < 4; j++) {
        float x = acc[mi][ni][j] + bv;
        if (EPI == EPI_GELU) x = 0.5f * x * (1.f + erff(x * 0.70710678118f));
        C[(row0 + j) * (size_t)N + col] = f2bf(x);
      }
    }
  }
}

// ---------------------------------------------------------------- block reduce
__device__ inline float2 block_sum2(float a, float b, float* sc) {
#pragma unroll
  for (int o = 32; o >= 1; o >>= 1) {
    a += __shfl_down(a, o);
    b += __shfl_down(b, o);
  }
  const int lane = threadIdx.x & 63, w = threadIdx.x >> 6;
  const int nw = blockDim.x >> 6;
  if (lane == 0) { sc[w * 2] = a; sc[w * 2 + 1] = b; }
  __syncthreads();
  float ra = 0.f, rb = 0.f;
  for (int i = 0; i < nw; i++) { ra += sc[i * 2]; rb += sc[i * 2 + 1]; }
  __syncthreads();
  return make_float2(ra, rb);
}

// ---------------------------------------------------------------- fused LN(q),LN(k) + 16x16 attention
__global__ __launch_bounds__(256)
void attn_ln(const short* __restrict__ qp, const short* __restrict__ kv,
             const float* __restrict__ lnqw, const float* __restrict__ lnqb,
             const float* __restrict__ lnkw, const float* __restrict__ lnkb,
             short* __restrict__ att) {
  __shared__ float qs[HID];
  __shared__ float ks[NH * 65];
  __shared__ float vs[HID];
  __shared__ float aw[256];
  __shared__ float red[8];
  const int t = threadIdx.x;
  const size_t row = blockIdx.x;

  short4v q4 = *(const short4v*)(qp + row * HID + t * 4);
  short4v k4 = *(const short4v*)(kv + row * 2048 + t * 4);
  short4v v4 = *(const short4v*)(kv + row * 2048 + 1024 + t * 4);
  float qv[4], kvv[4];
  float sq = 0.f, sqq = 0.f, sk = 0.f, skk = 0.f;
#pragma unroll
  for (int i = 0; i < 4; i++) {
    qv[i] = bf2f(q4[i]); sq += qv[i]; sqq += qv[i] * qv[i];
    kvv[i] = bf2f(k4[i]); sk += kvv[i]; skk += kvv[i] * kvv[i];
  }
  float2 rq = block_sum2(sq, sqq, red);
  float mq = rq.x / HID, vq = rq.y / HID - mq * mq;
  float rsq = rsqrtf(vq + 1e-5f);
  float2 rk = block_sum2(sk, skk, red);
  float mk = rk.x / HID, vv = rk.y / HID - mk * mk;
  float rsk = rsqrtf(vv + 1e-5f);
#pragma unroll
  for (int i = 0; i < 4; i++) {
    const int idx = t * 4 + i;
    qs[idx] = (qv[i] - mq) * rsq * lnqw[idx] + lnqb[idx];
    ks[(idx >> 6) * 65 + (idx & 63)] = (kvv[i] - mk) * rsk * lnkw[idx] + lnkb[idx];
    vs[idx] = bf2f(v4[i]);
  }
  __syncthreads();

  const int h = t >> 4, j = t & 15;
  float s = 0.f;
#pragma unroll 8
  for (int d = 0; d < 64; d++) s += qs[h * 64 + d] * ks[j * 65 + d];
  s *= 0.125f;
  float mx = s;
#pragma unroll
  for (int o = 8; o >= 1; o >>= 1) mx = fmaxf(mx, __shfl_xor(mx, o, 16));
  float e = __expf(s - mx);
  float sum = e;
#pragma unroll
  for (int o = 8; o >= 1; o >>= 1) sum += __shfl_xor(sum, o, 16);
  aw[t] = e / sum;
  __syncthreads();

  const int dB = (t & 15) * 4;
  float o0 = 0.f, o1 = 0.f, o2 = 0.f, o3 = 0.f;
#pragma unroll
  for (int jj = 0; jj < 16; jj++) {
    const float w = aw[h * 16 + jj];
    const float* vp = &vs[jj * 64 + dB];
    o0 += w * vp[0]; o1 += w * vp[1]; o2 += w * vp[2]; o3 += w * vp[3];
  }
  short4v o4;
  o4[0] = f2bf(o0); o4[1] = f2bf(o1); o4[2] = f2bf(o2); o4[3] = f2bf(o3);
  *(short4v*)(att + row * HID + h * 64 + dB) = o4;
}

// ---------------------------------------------------------------- gate
__global__ __launch_bounds__(256)
void gate_kernel(const short* __restrict__ hgc,
                 const float* __restrict__ wg2, const float* __restrict__ bg2,
                 const float* __restrict__ wc2, const float* __restrict__ bc2,
                 float* __restrict__ eg) {
  __shared__ float red[8];
  const int t = threadIdx.x;
  const size_t row = blockIdx.x;
  short4v g4 = *(const short4v*)(hgc + row * 2048 + t * 4);
  short4v c4 = *(const short4v*)(hgc + row * 2048 + 1024 + t * 4);
  float sg = 0.f, sc = 0.f;
#pragma unroll
  for (int i = 0; i < 4; i++) {
    sg += bf2f(g4[i]) * wg2[t * 4 + i];
    sc += bf2f(c4[i]) * wc2[t * 4 + i];
  }
  float2 r = block_sum2(sg, sc, red);
  if (t == 0) {
    float g = 1.f / (1.f + __expf(-(r.x + bg2[0])));
    float c = 1.f / (1.f + __expf(-(r.y + bc2[0])));
    eg[row] = g * c;
  }
}

// ---------------------------------------------------------------- final
__global__ __launch_bounds__(256)
void final_kernel(const short* __restrict__ opre, const float* __restrict__ qf,
                  const float* __restrict__ eg,
                  const float* __restrict__ lnow, const float* __restrict__ lnob,
                  float* __restrict__ out) {
  __shared__ float red[8];
  const int t = threadIdx.x;
  const size_t row = blockIdx.x;
  short8 o8 = *(const short8*)(opre + row * QD + t * 8);
  float x[8];
  float s = 0.f, ss = 0.f;
#pragma unroll
  for (int i = 0; i < 8; i++) { x[i] = bf2f(o8[i]); s += x[i]; ss += x[i] * x[i]; }
  float2 r = block_sum2(s, ss, red);
  float m = r.x / QD, v = r.y / QD - m * m;
  float rs = rsqrtf(v + 1e-5f);
  float g = eg[row];
  float4v oa, ob;
#pragma unroll
  for (int i = 0; i < 8; i++) {
    const int c = t * 8 + i;
    float y = (x[i] - m) * rs * lnow[c] + lnob[c];
    float r2 = qf[row * QD + c] + g * y;
    if (i < 4) oa[i] = r2; else ob[i - 4] = r2;
  }
  *(float4v*)(out + row * QD + t * 8) = oa;
  *(float4v*)(out + row * QD + t * 8 + 4) = ob;
}

// ---------------------------------------------------------------- launch
extern "C" void kernel_launch(void* const* d_in, const int* in_sizes, int n_in,
                              void* d_out, int out_size, void* d_ws, size_t ws_size,
                              hipStream_t stream) {
  const float* qf   = (const float*)d_in[0];
  const float* kf   = (const float*)d_in[1];
  const float* Wq   = (const float*)d_in[2];
  const float* bq   = (const float*)d_in[3];
  const float* lnqw = (const float*)d_in[4];
  const float* lnqb = (const float*)d_in[5];
  const float* Wk   = (const float*)d_in[6];
  const float* bk   = (const float*)d_in[7];
  const float* lnkw = (const float*)d_in[8];
  const float* lnkb = (const float*)d_in[9];
  const float* Wvk  = (const float*)d_in[12];
  const float* bvk  = (const float*)d_in[13];
  const float* Wo   = (const float*)d_in[14];
  const float* bo   = (const float*)d_in[15];
  const float* lnow = (const float*)d_in[16];
  const float* lnob = (const float*)d_in[17];
  const float* Wg1  = (const float*)d_in[18];
  const float* bg1  = (const float*)d_in[19];
  const float* Wg2  = (const float*)d_in[20];
  const float* bg2  = (const float*)d_in[21];
  const float* Wc1  = (const float*)d_in[22];
  const float* bc1  = (const float*)d_in[23];
  const float* Wc2  = (const float*)d_in[24];
  const float* bc2  = (const float*)d_in[25];

  const int rows = in_sizes[0] / QD;   // 16384

  char* ws = (char*)d_ws;
  size_t off = 0;
  auto alloc = [&](size_t bytes) -> char* {
    char* p = ws + off;
    off += (bytes + 255) & ~(size_t)255;
    return p;
  };
  short* cmb  = (short*)alloc((size_t)rows * CMBD * 2);
  short* wqb  = (short*)alloc((size_t)HID * QD * 2);
  short* wkv  = (short*)alloc((size_t)2 * HID * KD * 2);
  short* wob  = (short*)alloc((size_t)QD * HID * 2);
  short* wgc  = (short*)alloc((size_t)2 * HID * CMBD * 2);
  short* hgc  = (short*)alloc((size_t)rows * 2048 * 2);
  short* qp   = (short*)alloc((size_t)rows * HID * 2);
  short* kvp  = (short*)alloc((size_t)rows * 2048 * 2);
  float* eg   = (float*)alloc((size_t)rows * 4);
  float* bgc  = (float*)alloc(2048 * 4);
  float* bkv  = (float*)alloc(2048 * 4);
  short* att  = hgc;   // reuse after gate_kernel
  short* opre = cmb;   // reuse after last cmb-reading GEMM

  hipMemcpyAsync(bgc, bg1, HID * 4, hipMemcpyDeviceToDevice, stream);
  hipMemcpyAsync(bgc + HID, bc1, HID * 4, hipMemcpyDeviceToDevice, stream);
  hipMemcpyAsync(bkv, bk, HID * 4, hipMemcpyDeviceToDevice, stream);
  hipMemcpyAsync(bkv + HID, bvk, HID * 4, hipMemcpyDeviceToDevice, stream);

  cvt_concat<<<rows * 2, 256, 0, stream>>>(qf, cmb, QD / 4, CMBD);
  cvt_concat<<<rows, 256, 0, stream>>>(kf, cmb + QD, KD / 4, CMBD);
  cvt_bf16<<<(HID * QD / 4) / 256, 256, 0, stream>>>(Wq, wqb);
  cvt_bf16<<<(HID * KD / 4) / 256, 256, 0, stream>>>(Wk, wkv);
  cvt_bf16<<<(HID * KD / 4) / 256, 256, 0, stream>>>(Wvk, wkv + (size_t)HID * KD);
  cvt_bf16<<<(QD * HID / 4) / 256, 256, 0, stream>>>(Wo, wob);
  cvt_bf16<<<(HID * CMBD / 4) / 256, 256, 0, stream>>>(Wg1, wgc);
  cvt_bf16<<<(HID * CMBD / 4) / 256, 256, 0, stream>>>(Wc1, wgc + (size_t)HID * CMBD);

  // allow 128 KiB dynamic LDS (host-side attribute; not a stream op)
  hipFuncSetAttribute((const void*)gemm256<EPI_GELU>,
                      hipFuncAttributeMaxDynamicSharedMemorySize, 131072);
  hipFuncSetAttribute((const void*)gemm256<EPI_NONE>,
                      hipFuncAttributeMaxDynamicSharedMemorySize, 131072);

  const dim3 blk(512);
  const int mt = rows / 256;   // 64
  const size_t lds = 131072;

  gemm256<EPI_GELU><<<dim3(2048 / 256, mt), blk, lds, stream>>>(cmb, CMBD, wgc, bgc, hgc, 2048, CMBD);
  gate_kernel<<<rows, 256, 0, stream>>>(hgc, Wg2, bg2, Wc2, bc2, eg);
  gemm256<EPI_NONE><<<dim3(1024 / 256, mt), blk, lds, stream>>>(cmb, CMBD, wqb, bq, qp, 1024, QD);
  gemm256<EPI_NONE><<<dim3(2048 / 256, mt), blk, lds, stream>>>(cmb + QD, CMBD, wkv, bkv, kvp, 2048, KD);
  attn_ln<<<rows, 256, 0, stream>>>(qp, kvp, lnqw, lnqb, lnkw, lnkb, att);
  gemm256<EPI_NONE><<<dim3(2048 / 256, mt), blk, lds, stream>>>(att, HID, wob, bo, opre, 2048, HID);
  final_kernel<<<rows, 256, 0, stream>>>(opre, qf, eg, lnow, lnob, (float*)d_out);
}